// Round 19
// baseline (182.840 us; speedup 1.0000x reference)
//
#include <hip/hip_runtime.h>
#include <stdint.h>

// ---------------------------------------------------------------------------
// CausalSelfAttention fused pipeline for MI355X (gfx950)
//   B=4, T=2048, C=1024, H=16, hd=64
// Round 19: gemmQKV BK 32->64 (16 K-steps instead of 32): halves per-step
//   fixed overhead (2-barrier rendezvous + exposed staging latency, measured
//   ~2100cyc/step vs 640cyc MFMA). Double-buffer depth-1, vmcnt(6|0),
//   attn-proven 128B-row swizzle b^(((b>>7)&7)<<4), LDS 96KB, lb(512,2).
//   attn / gemm_out / prep unchanged (round-14 proven, 174.2us reproduced).
// ---------------------------------------------------------------------------

typedef __bf16 bf16x8 __attribute__((ext_vector_type(8)));
typedef float f32x4 __attribute__((ext_vector_type(4)));
typedef unsigned short u16x8 __attribute__((ext_vector_type(8)));

#define DEVINL static __device__ __forceinline__

DEVINL unsigned short f2b(float f) {
  __bf16 h = (__bf16)f;           // RNE
  return __builtin_bit_cast(unsigned short, h);
}

DEVINL void gld16(const void* g, void* l) {
  __builtin_amdgcn_global_load_lds(
      (const __attribute__((address_space(1))) void*)g,
      (__attribute__((address_space(3))) void*)l, 16, 0, 0);
}

DEVINL f32x4 mfma16(bf16x8 a, bf16x8 b, f32x4 c) {
  return __builtin_amdgcn_mfma_f32_16x16x32_bf16(a, b, c, 0, 0, 0);
}

#define SCHED_FENCE() __builtin_amdgcn_sched_barrier(0)

// --------------------------------------------- prep: cast x + transpose Ws
__global__ __launch_bounds__(256) void k_prep(const float* __restrict__ x,
                                              unsigned short* __restrict__ xb,
                                              const float* __restrict__ wqkv,
                                              unsigned short* __restrict__ wqkvT,
                                              const float* __restrict__ wproj,
                                              unsigned short* __restrict__ wprojT) {
  int blk = blockIdx.x;
  int tid = threadIdx.x;
  if (blk < 4096) {
    int i = blk * 256 + tid;
    const float4* p = (const float4*)x + (size_t)i * 2;
    float4 a = p[0], b = p[1];
    u16x8 o;
    o[0] = f2b(a.x); o[1] = f2b(a.y); o[2] = f2b(a.z); o[3] = f2b(a.w);
    o[4] = f2b(b.x); o[5] = f2b(b.y); o[6] = f2b(b.z); o[7] = f2b(b.w);
    *(u16x8*)(xb + (size_t)i * 8) = o;
    return;
  }
  __shared__ float t[64][65];
  const float* in;
  unsigned short* out;
  int R, C, ci, ri;
  if (blk < 4864) {
    int bi = blk - 4096;
    in = wqkv; out = wqkvT; R = 1024; C = 3072;
    ci = (bi % 48) * 64; ri = (bi / 48) * 64;
  } else {
    int bi = blk - 4864;
    in = wproj; out = wprojT; R = 1024; C = 1024;
    ci = (bi % 16) * 64; ri = (bi / 16) * 64;
  }
#pragma unroll
  for (int j = 0; j < 4; ++j) {
    int c = tid + j * 256;           // 0..1023 float4 chunks of the 64x64 tile
    int row = c >> 4;
    int col = (c & 15) * 4;
    float4 v = *(const float4*)(in + (size_t)(ri + row) * C + ci + col);
    t[row][col] = v.x; t[row][col + 1] = v.y; t[row][col + 2] = v.z; t[row][col + 3] = v.w;
  }
  __syncthreads();
  int cc = tid >> 2;                 // output row (C index), 0..63
  int seg = (tid & 3) * 16;
  u16x8 o0, o1;
#pragma unroll
  for (int j = 0; j < 8; ++j) o0[j] = f2b(t[seg + j][cc]);
#pragma unroll
  for (int j = 0; j < 8; ++j) o1[j] = f2b(t[seg + 8 + j][cc]);
  unsigned short* dst = out + (size_t)(ci + cc) * R + ri + seg;
  *(u16x8*)dst = o0;
  *(u16x8*)(dst + 8) = o1;
}

// ------------------------------------------------------- GEMM1: QKV scatter
// A [8192][1024] bf16, Bt [3072][1024] bf16. 256x128 tile, BK=64, 8 waves.
// 16 K-steps; double-buffer depth-1 counted vmcnt (6 steady / 0 last);
// double-barrier discipline. LDS rows 128B with attn-proven XOR swizzle
// b^(((b>>7)&7)<<4) both sides. Bijective XCD remap, bm-chunked.
// Scatters q/k per-head [bh][t][d] (q scaled) + V^T [bh][d][t] packed 8B.
__global__ __launch_bounds__(512, 2)
void k_gemmQKV(const unsigned short* __restrict__ A,
               const unsigned short* __restrict__ Bt,
               unsigned short* __restrict__ qo,
               unsigned short* __restrict__ ko,
               unsigned short* __restrict__ vo,
               float qscale) {
  const int K = 1024, N = 3072;
  __shared__ unsigned short As[2][256 * 64];   // 64 KB  [256 rows][128B]
  __shared__ unsigned short Bs[2][128 * 64];   // 32 KB  [128 rows][128B]
  int tid = threadIdx.x;
  int w = tid >> 6, lane = tid & 63, l15 = lane & 15, l4 = lane >> 4;
  int nwg = gridDim.x;
  int gx = N >> 7;                     // 24
  int lin = blockIdx.x;
  int nx = nwg >> 3, rr = nwg & 7;
  int xcd = lin & 7, idx = lin >> 3;
  int wgid = (xcd < rr ? xcd * (nx + 1) : rr * (nx + 1) + (xcd - rr) * nx) + idx;
  int bn = wgid % gx, bm = wgid / gx;
  int wr = (w >> 1) * 64, wc = (w & 1) * 64;   // M-sub 0..192, N-sub 0..64
  f32x4 acc[4][4];
#pragma unroll
  for (int i = 0; i < 4; ++i)
#pragma unroll
    for (int j = 0; j < 4; ++j) acc[i][j] = (f32x4){0.f, 0.f, 0.f, 0.f};
  const char* Ab = (const char*)(A + (size_t)bm * 256 * K);
  const char* Bb = (const char*)(Bt + (size_t)bn * 128 * K);
  const size_t Kb2 = (size_t)K * 2;    // bytes per row
  // staging: A tile = 32KB = 2048 chunks (4/thread); B = 16KB = 1024 (2/thread)
  // LDS dest linear Lb; global source from pre-swizzled Nb = swz(Lb).
  int LbA0 = tid * 16, LbA1 = (tid + 512) * 16;
  int LbA2 = (tid + 1024) * 16, LbA3 = (tid + 1536) * 16;
  int LbB0 = tid * 16, LbB1 = (tid + 512) * 16;
  int NA0 = LbA0 ^ (((LbA0 >> 7) & 7) << 4);
  int NA1 = LbA1 ^ (((LbA1 >> 7) & 7) << 4);
  int NA2 = LbA2 ^ (((LbA2 >> 7) & 7) << 4);
  int NA3 = LbA3 ^ (((LbA3 >> 7) & 7) << 4);
  int NB0 = LbB0 ^ (((LbB0 >> 7) & 7) << 4);
  int NB1 = LbB1 ^ (((LbB1 >> 7) & 7) << 4);
  int rA0 = NA0 >> 7, oA0 = NA0 & 127;
  int rA1 = NA1 >> 7, oA1 = NA1 & 127;
  int rA2 = NA2 >> 7, oA2 = NA2 & 127;
  int rA3 = NA3 >> 7, oA3 = NA3 & 127;
  int rB0 = NB0 >> 7, oB0 = NB0 & 127;
  int rB1 = NB1 >> 7, oB1 = NB1 & 127;

  auto stage = [&](int kt, int buf) {  // kt in elements (multiple of 64)
    gld16(Ab + (size_t)rA0 * Kb2 + kt * 2 + oA0, (char*)As[buf] + LbA0);
    gld16(Ab + (size_t)rA1 * Kb2 + kt * 2 + oA1, (char*)As[buf] + LbA1);
    gld16(Ab + (size_t)rA2 * Kb2 + kt * 2 + oA2, (char*)As[buf] + LbA2);
    gld16(Ab + (size_t)rA3 * Kb2 + kt * 2 + oA3, (char*)As[buf] + LbA3);
    gld16(Bb + (size_t)rB0 * Kb2 + kt * 2 + oB0, (char*)Bs[buf] + LbB0);
    gld16(Bb + (size_t)rB1 * Kb2 + kt * 2 + oB1, (char*)Bs[buf] + LbB1);
  };

  const int nkt = K >> 6;              // 16
  stage(0, 0);
  SCHED_FENCE();
  for (int t = 0; t < nkt; ++t) {
    int cur = t & 1;
    if (t) {                           // WAR: all waves done reading buf[cur]
      SCHED_FENCE();
      __builtin_amdgcn_s_barrier();
      SCHED_FENCE();
    }
    if (t + 1 < nkt) {
      stage((t + 1) * 64, cur ^ 1);
      SCHED_FENCE();
      asm volatile("s_waitcnt vmcnt(6)" ::: "memory");  // tile t complete
    } else {
      SCHED_FENCE();
      asm volatile("s_waitcnt vmcnt(0)" ::: "memory");
    }
    SCHED_FENCE();
    __builtin_amdgcn_s_barrier();      // RAW: buf[cur] ready for all waves
    SCHED_FENCE();
    const char* Ac = (const char*)As[cur];
    const char* Bc = (const char*)Bs[cur];
#pragma unroll
    for (int ks = 0; ks < 2; ++ks) {
      bf16x8 af[4], bfr[4];
#pragma unroll
      for (int m = 0; m < 4; ++m) {
        int nat = (wr + m * 16 + l15) * 128 + ks * 64 + l4 * 16;
        af[m] = *(const bf16x8*)(Ac + (nat ^ (((nat >> 7) & 7) << 4)));
      }
#pragma unroll
      for (int n = 0; n < 4; ++n) {
        int nat = (wc + n * 16 + l15) * 128 + ks * 64 + l4 * 16;
        bfr[n] = *(const bf16x8*)(Bc + (nat ^ (((nat >> 7) & 7) << 4)));
      }
      __builtin_amdgcn_s_setprio(1);
#pragma unroll
      for (int m = 0; m < 4; ++m)
#pragma unroll
        for (int n = 0; n < 4; ++n)
          acc[m][n] = mfma16(af[m], bfr[n], acc[m][n]);
      __builtin_amdgcn_s_setprio(0);
    }
  }
  // epilogue scatter: D col = lane&15, row = (lane>>4)*4 + reg
#pragma unroll
  for (int m = 0; m < 4; ++m) {
    int grow0 = bm * 256 + wr + m * 16 + l4 * 4;
#pragma unroll
    for (int n = 0; n < 4; ++n) {
      int gcol = bn * 128 + wc + n * 16 + l15;
      int which = gcol >> 10, rem = gcol & 1023;
      int h = rem >> 6, d = rem & 63;
      int b = grow0 >> 11, t0 = grow0 & 2047;
      if (which == 2) {
        // V^T [bh][d][t]: 4 consecutive-t bf16 -> one 8B store
        uint32_t lo = (uint32_t)f2b(acc[m][n][0]) | ((uint32_t)f2b(acc[m][n][1]) << 16);
        uint32_t hi = (uint32_t)f2b(acc[m][n][2]) | ((uint32_t)f2b(acc[m][n][3]) << 16);
        size_t off = (((size_t)(b * 16 + h)) * 64 + d) * 2048 + t0;
        *(uint2*)(vo + off) = make_uint2(lo, hi);
      } else {
        size_t off = (((size_t)(b * 16 + h)) * 2048 + t0) * 64 + d;
#pragma unroll
        for (int r = 0; r < 4; ++r) {
          float val = acc[m][n][r];
          if (which == 0) qo[off + (size_t)r * 64] = f2b(val * qscale);
          else            ko[off + (size_t)r * 64] = f2b(val);
        }
      }
    }
  }
}

// ------------------------------------------------ GEMM2: out-proj, fp32 out
// A [M][K] bf16, Bt [N][K] bf16. 128x128 tile, BK=32, 4 waves. Triple-buffer
// depth-2 counted vmcnt + both-sides swizzle.  [round-11/14 proven, ~20us]
__global__ __launch_bounds__(256) void k_gemm_out(const unsigned short* __restrict__ A,
                                                  const unsigned short* __restrict__ Bt,
                                                  int M, int N, int K,
                                                  float* __restrict__ Cf) {
  __shared__ unsigned short As[3][128 * 32];   // 24 KB
  __shared__ unsigned short Bs[3][128 * 32];   // 24 KB
  int tid = threadIdx.x;
  int w = tid >> 6, lane = tid & 63, l15 = lane & 15, l4 = lane >> 4;
  int nwg = gridDim.x;
  int gx = N >> 7;
  int lin = blockIdx.x;
  int nx = nwg >> 3, rr = nwg & 7;
  int xcd = lin & 7, idx = lin >> 3;
  int wgid = (xcd < rr ? xcd * (nx + 1) : rr * (nx + 1) + (xcd - rr) * nx) + idx;
  int bn = wgid % gx, bm = wgid / gx;
  int wr = (w >> 1) * 64, wc = (w & 1) * 64;
  f32x4 acc[4][4];
#pragma unroll
  for (int i = 0; i < 4; ++i)
#pragma unroll
    for (int j = 0; j < 4; ++j) acc[i][j] = (f32x4){0.f, 0.f, 0.f, 0.f};
  const char* Ab = (const char*)(A + (size_t)bm * 128 * K);
  const char* Bb = (const char*)(Bt + (size_t)bn * 128 * K);
  int Lb0 = tid * 16, Lb1 = (tid + 256) * 16;
  int Nb0 = Lb0 ^ (((Lb0 >> 7) & 3) << 4);
  int Nb1 = Lb1 ^ (((Lb1 >> 7) & 3) << 4);
  int rA0 = Nb0 >> 6, o0 = Nb0 & 63;
  int rA1 = Nb1 >> 6, o1 = Nb1 & 63;

  auto stage = [&](int kt, int buf) {
    gld16(Ab + ((size_t)rA0 * K + kt) * 2 + o0, (char*)As[buf] + Lb0);
    gld16(Bb + ((size_t)rA0 * K + kt) * 2 + o0, (char*)Bs[buf] + Lb0);
    gld16(Ab + ((size_t)rA1 * K + kt) * 2 + o1, (char*)As[buf] + Lb1);
    gld16(Bb + ((size_t)rA1 * K + kt) * 2 + o1, (char*)Bs[buf] + Lb1);
  };

  const int nkt = K >> 5;
  stage(0, 0);
  stage(32, 1);
  SCHED_FENCE();
  for (int t = 0; t < nkt; ++t) {
    int cur = t - (t / 3) * 3;
    if (t) {
      SCHED_FENCE();
      __builtin_amdgcn_s_barrier();
      SCHED_FENCE();
    }
    if (t + 2 < nkt) {
      int nb = (t + 2) - ((t + 2) / 3) * 3;
      stage((t + 2) * 32, nb);
      SCHED_FENCE();
      asm volatile("s_waitcnt vmcnt(8)" ::: "memory");
    } else if (t + 1 < nkt) {
      SCHED_FENCE();
      asm volatile("s_waitcnt vmcnt(4)" ::: "memory");
    } else {
      SCHED_FENCE();
      asm volatile("s_waitcnt vmcnt(0)" ::: "memory");
    }
    SCHED_FENCE();
    __builtin_amdgcn_s_barrier();
    SCHED_FENCE();
    const char* Ac = (const char*)As[cur];
    const char* Bc = (const char*)Bs[cur];
    bf16x8 af[4], bfr[4];
#pragma unroll
    for (int m = 0; m < 4; ++m) {
      int nat = (wr + m * 16 + l15) * 64 + l4 * 16;
      af[m] = *(const bf16x8*)(Ac + (nat ^ (((nat >> 7) & 3) << 4)));
    }
#pragma unroll
    for (int n = 0; n < 4; ++n) {
      int nat = (wc + n * 16 + l15) * 64 + l4 * 16;
      bfr[n] = *(const bf16x8*)(Bc + (nat ^ (((nat >> 7) & 3) << 4)));
    }
    __builtin_amdgcn_s_setprio(1);
#pragma unroll
    for (int m = 0; m < 4; ++m)
#pragma unroll
      for (int n = 0; n < 4; ++n)
        acc[m][n] = mfma16(af[m], bfr[n], acc[m][n]);
    __builtin_amdgcn_s_setprio(0);
  }
#pragma unroll
  for (int m = 0; m < 4; ++m) {
    int grow0 = bm * 128 + wr + m * 16 + l4 * 4;
#pragma unroll
    for (int n = 0; n < 4; ++n) {
      int gcol = bn * 128 + wc + n * 16 + l15;
#pragma unroll
      for (int r = 0; r < 4; ++r)
        Cf[(size_t)(grow0 + r) * N + gcol] = acc[m][n][r];
    }
  }
}

// ------------------------------------------------------------ flash attention
// Q,K: [bh][2048][64] bf16 (Q pre-scaled by 0.125*log2e); Vt: [bh][64][2048].
// 8 waves x 16 q-rows (QBLK=128); ONE q-tile per block, grid 1024,
// heavy-first. K/V double-buffered; double-barrier counted vmcnt(2).
// Fully-masked waves skip compute. LDS XOR swizzle: byte ^ ((row&7)<<4).
// [round-14 proven config — 72 us]
__global__ __launch_bounds__(512) void k_attn(const unsigned short* __restrict__ Q,
                                              const unsigned short* __restrict__ Kt,
                                              const unsigned short* __restrict__ Vt,
                                              unsigned short* __restrict__ AO) {
  __shared__ unsigned short Ks[2][4096];   // 16 KB  [64 kv][64 d]
  __shared__ unsigned short Vs[2][4096];   // 16 KB  [64 d][64 kv]
  __shared__ unsigned short Ps[8192];      // 16 KB  8 waves x [16 q][64 kv]
  int tid = threadIdx.x;
  int w = tid >> 6, lane = tid & 63, l15 = lane & 15, l4 = lane >> 4;
  int lin = blockIdx.x;
  int xcd = lin & 7, jj = lin >> 3;        // jj in 0..127
  int bh = xcd * 8 + (jj & 7);
  int qi = 15 - (jj >> 3);                 // 15 (heavy) .. 0 (light)
  const char* Kb = (const char*)(Kt + (size_t)bh * 2048 * 64);
  const char* Vb = (const char*)(Vt + (size_t)bh * 64 * 2048);
  const int swp = (l15 & 7) << 4;          // P-row swizzle for this lane
  char* Pw = (char*)Ps + w * 2048;
  int b = bh >> 4, h = bh & 15;

  int Lb0 = tid * 16;
  int Nb0 = Lb0 ^ (((Lb0 >> 7) & 7) << 4);
  int d0 = Nb0 >> 7, in0 = Nb0 & 127;

  auto stage = [&](int t, int buf) {
    size_t kv0 = (size_t)t * 64;
    gld16(Kb + kv0 * 128 + Nb0, (char*)Ks[buf] + Lb0);
    gld16(Vb + (size_t)d0 * 4096 + kv0 * 2 + in0, (char*)Vs[buf] + Lb0);
  };

  int q0 = qi * 128;
  const unsigned short* Qb = Q + ((size_t)bh * 2048 + q0 + w * 16) * 64;
  bf16x8 qf0 = *(const bf16x8*)((const char*)Qb + l15 * 128 + l4 * 16);
  bf16x8 qf1 = *(const bf16x8*)((const char*)Qb + l15 * 128 + 64 + l4 * 16);
  f32x4 o[4];
#pragma unroll
  for (int i = 0; i < 4; ++i) o[i] = (f32x4){0.f, 0.f, 0.f, 0.f};
  float mrow = -1e30f, lrow = 0.f;       // per-lane state for q = l15
  const int ntiles = 2 * qi + 2;
  const int qgmin = q0 + w * 16;         // this wave's lowest q row
  const int qg = qgmin + l15;            // per-lane q row
  stage(0, 0);
  SCHED_FENCE();
  for (int it = 0; it < ntiles; ++it) {
    int cur = it & 1;
    if (it) {                            // WAR: all waves done reading buf[cur^1]
      SCHED_FENCE();
      __builtin_amdgcn_s_barrier();
      SCHED_FENCE();
    }
    if (it + 1 < ntiles) {
      stage(it + 1, cur ^ 1);
      SCHED_FENCE();
      asm volatile("s_waitcnt vmcnt(2)" ::: "memory");  // tile it complete
    } else {
      SCHED_FENCE();
      asm volatile("s_waitcnt vmcnt(0)" ::: "memory");  // last tile: drain
    }
    SCHED_FENCE();
    __builtin_amdgcn_s_barrier();        // RAW: buf[cur] ready for all waves
    SCHED_FENCE();
    if (it * 64 <= qgmin + 15) {         // wave-uniform: not fully masked
      const char* Kc = (const char*)Ks[cur];
      const char* Vc = (const char*)Vs[cur];
      // S^T = K Q^T: lane holds s[c][r] = S[q=l15][kv=it*64+c*16+l4*4+r]
      f32x4 s[4];
      __builtin_amdgcn_s_setprio(1);
#pragma unroll
      for (int c = 0; c < 4; ++c) {
        int row = c * 16 + l15;
        int base = row * 128 + l4 * 16;
        int sw = (row & 7) << 4;
        bf16x8 k0 = *(const bf16x8*)(Kc + (base ^ sw));
        bf16x8 k1 = *(const bf16x8*)(Kc + ((base + 64) ^ sw));
        f32x4 t = mfma16(k0, qf0, (f32x4){0.f, 0.f, 0.f, 0.f});
        s[c] = mfma16(k1, qf1, t);
      }
      __builtin_amdgcn_s_setprio(0);
      if (it * 64 + 63 > qgmin) {        // diagonal-intersecting tile: mask
#pragma unroll
        for (int c = 0; c < 4; ++c) {
          int kvb = it * 64 + c * 16 + l4 * 4;
#pragma unroll
          for (int r = 0; r < 4; ++r)
            if (kvb + r > qg) s[c][r] = -1e30f;
        }
      }
      // online softmax: lane-local 16 + 2 shuffles
      float mx = fmaxf(fmaxf(fmaxf(s[0][0], s[0][1]), fmaxf(s[0][2], s[0][3])),
                       fmaxf(fmaxf(s[1][0], s[1][1]), fmaxf(s[1][2], s[1][3])));
      mx = fmaxf(mx, fmaxf(fmaxf(fmaxf(s[2][0], s[2][1]), fmaxf(s[2][2], s[2][3])),
                           fmaxf(fmaxf(s[3][0], s[3][1]), fmaxf(s[3][2], s[3][3]))));
      mx = fmaxf(mx, __shfl_xor(mx, 16));
      mx = fmaxf(mx, __shfl_xor(mx, 32));
      float mn = fmaxf(mrow, mx);
      float corr = __builtin_amdgcn_exp2f(mrow - mn);
      mrow = mn;
      float rs = 0.f;
#pragma unroll
      for (int c = 0; c < 4; ++c) {
        float p0 = __builtin_amdgcn_exp2f(s[c][0] - mn);
        float p1 = __builtin_amdgcn_exp2f(s[c][1] - mn);
        float p2 = __builtin_amdgcn_exp2f(s[c][2] - mn);
        float p3 = __builtin_amdgcn_exp2f(s[c][3] - mn);
        rs += (p0 + p1) + (p2 + p3);
        uint32_t lo = (uint32_t)f2b(p0) | ((uint32_t)f2b(p1) << 16);
        uint32_t hi = (uint32_t)f2b(p2) | ((uint32_t)f2b(p3) << 16);
        *(uint2*)(Pw + ((l15 * 128 + c * 32 + l4 * 8) ^ swp)) = make_uint2(lo, hi);
      }
      rs += __shfl_xor(rs, 16);
      rs += __shfl_xor(rs, 32);
      lrow = lrow * corr + rs;
      float corr_r[4];
#pragma unroll
      for (int r = 0; r < 4; ++r) corr_r[r] = __shfl(corr, l4 * 4 + r);
#pragma unroll
      for (int dc = 0; dc < 4; ++dc)
#pragma unroll
        for (int r = 0; r < 4; ++r) o[dc][r] *= corr_r[r];
      // O += P V
      bf16x8 pa[2];
#pragma unroll
      for (int kc = 0; kc < 2; ++kc)
        pa[kc] = *(const bf16x8*)(Pw + ((l15 * 128 + kc * 64 + l4 * 16) ^ swp));
      __builtin_amdgcn_s_setprio(1);
#pragma unroll
      for (int dc = 0; dc < 4; ++dc) {
#pragma unroll
        for (int kc = 0; kc < 2; ++kc) {
          int vrow = dc * 16 + l15;
          int vnat = vrow * 128 + kc * 64 + l4 * 16;
          bf16x8 vb = *(const bf16x8*)(Vc + (vnat ^ ((vrow & 7) << 4)));
          o[dc] = mfma16(pa[kc], vb, o[dc]);
        }
      }
      __builtin_amdgcn_s_setprio(0);
    }
  }
  float inv[4];
#pragma unroll
  for (int r = 0; r < 4; ++r) inv[r] = 1.f / __shfl(lrow, l4 * 4 + r);
#pragma unroll
  for (int dc = 0; dc < 4; ++dc) {
#pragma unroll
    for (int r = 0; r < 4; ++r) {
      int t = q0 + w * 16 + l4 * 4 + r;
      AO[((size_t)(b * 2048 + t)) * 1024 + h * 64 + dc * 16 + l15] =
          f2b(o[dc][r] * inv[r]);
    }
  }
}

// ---------------------------------------------------------------------------
extern "C" void kernel_launch(void* const* d_in, const int* in_sizes, int n_in,
                              void* d_out, int out_size, void* d_ws, size_t ws_size,
                              hipStream_t stream) {
  const float* x      = (const float*)d_in[0];   // [4,2048,1024]
  const float* w_qkv  = (const float*)d_in[1];   // [1024,3072]
  const float* w_proj = (const float*)d_in[2];   // [1024,1024]
  float* out = (float*)d_out;                    // [4,2048,1024] f32
  char* ws = (char*)d_ws;
  const size_t MB = 1024 * 1024;
  // xb and ao alias (ao written by attn after gemm1 consumed xb).
  unsigned short* xb     = (unsigned short*)(ws);            // 16MB [8192][1024]
  unsigned short* ao     = (unsigned short*)(ws);            // 16MB [8192][1024]
  unsigned short* wqkvT  = (unsigned short*)(ws + 16 * MB);  // 6MB [3072][1024]
  unsigned short* wprojT = (unsigned short*)(ws + 22 * MB);  // 2MB [1024][1024]
  unsigned short* q      = (unsigned short*)(ws + 24 * MB);  // 16MB [64][2048][64]
  unsigned short* k      = (unsigned short*)(ws + 40 * MB);  // 16MB
  unsigned short* vT     = (unsigned short*)(ws + 56 * MB);  // 16MB [64][64][2048]

  const float qscale = 0.125f * 1.44269504088896f;  // hd^-0.5 * log2(e)
  k_prep<<<5120, 256, 0, stream>>>(x, xb, w_qkv, wqkvT, w_proj, wprojT);
  k_gemmQKV<<<768, 512, 0, stream>>>(xb, wqkvT, q, k, vT, qscale);
  k_attn<<<1024, 512, 0, stream>>>(q, k, vT, ao);
  k_gemm_out<<<512, 256, 0, stream>>>(ao, wprojT, 8192, 1024, 1024, out);
}

// Round 20
// 173.937 us; speedup vs baseline: 1.0512x; 1.0512x over previous
//
#include <hip/hip_runtime.h>
#include <stdint.h>

// ---------------------------------------------------------------------------
// CausalSelfAttention fused pipeline for MI355X (gfx950)
//   B=4, T=2048, C=1024, H=16, hd=64
// Round 20: FINAL — exact round-14/18 best-measured configuration (174.1 us,
//   reproduced 174.2). Variants tested and rejected with counter evidence:
//   r15 single-barrier (-7us attn), r16 256^2 gemm_out (1 blk/CU, -5us),
//   r17 double-buf gemmQKV (neutral), r19 BK=64 (96KB LDS -> 1 blk/CU,
//   FETCH +45%, -6us). Remaining headroom (gemmQKV 27% MfmaUtil, attn 54%
//   VALUBusy) requires the co-designed 8-phase schedule — a ground-up
//   rewrite, not an incremental edit on this structure.
//   - prep: fused cast + W transposes (5120 blocks)
//   - gemmQKV: 256x128, 8 waves, triple-buffer depth-2 (vmcnt 6|3|0),
//     double-barrier, both-sides swizzle, bm-chunked XCD remap
//   - attn: QBLK=128, 8 waves, grid 1024 heavy-first, dbuf vmcnt(2)
//   - gemm_out: 128x128, 4 waves, triple-buffer depth-2 (vmcnt 8|4|0)
// ---------------------------------------------------------------------------

typedef __bf16 bf16x8 __attribute__((ext_vector_type(8)));
typedef float f32x4 __attribute__((ext_vector_type(4)));
typedef unsigned short u16x8 __attribute__((ext_vector_type(8)));

#define DEVINL static __device__ __forceinline__

DEVINL unsigned short f2b(float f) {
  __bf16 h = (__bf16)f;           // RNE
  return __builtin_bit_cast(unsigned short, h);
}

DEVINL void gld16(const void* g, void* l) {
  __builtin_amdgcn_global_load_lds(
      (const __attribute__((address_space(1))) void*)g,
      (__attribute__((address_space(3))) void*)l, 16, 0, 0);
}

DEVINL f32x4 mfma16(bf16x8 a, bf16x8 b, f32x4 c) {
  return __builtin_amdgcn_mfma_f32_16x16x32_bf16(a, b, c, 0, 0, 0);
}

#define SCHED_FENCE() __builtin_amdgcn_sched_barrier(0)

// --------------------------------------------- prep: cast x + transpose Ws
// blocks 0..4095: x f32 -> bf16 (8 elems/thread)
// blocks 4096..4863: w_qkv [1024][3072] -> [3072][1024] bf16 (64x64 tiles)
// blocks 4864..5119: w_proj [1024][1024] -> [1024][1024] bf16
__global__ __launch_bounds__(256) void k_prep(const float* __restrict__ x,
                                              unsigned short* __restrict__ xb,
                                              const float* __restrict__ wqkv,
                                              unsigned short* __restrict__ wqkvT,
                                              const float* __restrict__ wproj,
                                              unsigned short* __restrict__ wprojT) {
  int blk = blockIdx.x;
  int tid = threadIdx.x;
  if (blk < 4096) {
    int i = blk * 256 + tid;
    const float4* p = (const float4*)x + (size_t)i * 2;
    float4 a = p[0], b = p[1];
    u16x8 o;
    o[0] = f2b(a.x); o[1] = f2b(a.y); o[2] = f2b(a.z); o[3] = f2b(a.w);
    o[4] = f2b(b.x); o[5] = f2b(b.y); o[6] = f2b(b.z); o[7] = f2b(b.w);
    *(u16x8*)(xb + (size_t)i * 8) = o;
    return;
  }
  __shared__ float t[64][65];
  const float* in;
  unsigned short* out;
  int R, C, ci, ri;
  if (blk < 4864) {
    int bi = blk - 4096;
    in = wqkv; out = wqkvT; R = 1024; C = 3072;
    ci = (bi % 48) * 64; ri = (bi / 48) * 64;
  } else {
    int bi = blk - 4864;
    in = wproj; out = wprojT; R = 1024; C = 1024;
    ci = (bi % 16) * 64; ri = (bi / 16) * 64;
  }
#pragma unroll
  for (int j = 0; j < 4; ++j) {
    int c = tid + j * 256;           // 0..1023 float4 chunks of the 64x64 tile
    int row = c >> 4;
    int col = (c & 15) * 4;
    float4 v = *(const float4*)(in + (size_t)(ri + row) * C + ci + col);
    t[row][col] = v.x; t[row][col + 1] = v.y; t[row][col + 2] = v.z; t[row][col + 3] = v.w;
  }
  __syncthreads();
  int cc = tid >> 2;                 // output row (C index), 0..63
  int seg = (tid & 3) * 16;
  u16x8 o0, o1;
#pragma unroll
  for (int j = 0; j < 8; ++j) o0[j] = f2b(t[seg + j][cc]);
#pragma unroll
  for (int j = 0; j < 8; ++j) o1[j] = f2b(t[seg + 8 + j][cc]);
  unsigned short* dst = out + (size_t)(ci + cc) * R + ri + seg;
  *(u16x8*)dst = o0;
  *(u16x8*)(dst + 8) = o1;
}

// ------------------------------------------------------- GEMM1: QKV scatter
// A [8192][1024] bf16, Bt [3072][1024] bf16. 256x128 tile, BK=32, 8 waves
// (4M x 2N of 64x64). Triple-buffered counted-vmcnt K-loop (stage t+2,
// vmcnt(6) steady), double-barrier. Both-sides XOR swizzle. Bijective XCD
// remap, bm-chunked. Scatters q/k per-head [bh][t][d] (q scaled) and
// V transposed [bh][d][t] via packed 8B stores.   [round-13/14 proven]
__global__ __launch_bounds__(512, 4)
void k_gemmQKV(const unsigned short* __restrict__ A,
               const unsigned short* __restrict__ Bt,
               unsigned short* __restrict__ qo,
               unsigned short* __restrict__ ko,
               unsigned short* __restrict__ vo,
               float qscale) {
  const int K = 1024, N = 3072;
  __shared__ unsigned short As[3][256 * 32];   // 48 KB
  __shared__ unsigned short Bs[3][128 * 32];   // 24 KB
  int tid = threadIdx.x;
  int w = tid >> 6, lane = tid & 63, l15 = lane & 15, l4 = lane >> 4;
  int nwg = gridDim.x;
  int gx = N >> 7;                     // 24
  int lin = blockIdx.x;
  int nx = nwg >> 3, rr = nwg & 7;
  int xcd = lin & 7, idx = lin >> 3;
  int wgid = (xcd < rr ? xcd * (nx + 1) : rr * (nx + 1) + (xcd - rr) * nx) + idx;
  int bn = wgid % gx, bm = wgid / gx;
  int wr = (w >> 1) * 64, wc = (w & 1) * 64;   // M-sub 0..192, N-sub 0..64
  f32x4 acc[4][4];
#pragma unroll
  for (int i = 0; i < 4; ++i)
#pragma unroll
    for (int j = 0; j < 4; ++j) acc[i][j] = (f32x4){0.f, 0.f, 0.f, 0.f};
  const char* Ab = (const char*)(A + (size_t)bm * 256 * K);
  const char* Bb = (const char*)(Bt + (size_t)bn * 128 * K);
  const size_t Kb2 = (size_t)K * 2;    // bytes per row
  int LbA0 = tid * 16, LbA1 = (tid + 512) * 16, LbB = tid * 16;
  int NA0 = LbA0 ^ (((LbA0 >> 7) & 3) << 4);
  int NA1 = LbA1 ^ (((LbA1 >> 7) & 3) << 4);
  int NB  = LbB  ^ (((LbB  >> 7) & 3) << 4);
  int rA0 = NA0 >> 6, oA0 = NA0 & 63;
  int rA1 = NA1 >> 6, oA1 = NA1 & 63;
  int rB  = NB  >> 6, oB  = NB  & 63;

  auto stage = [&](int kt, int buf) {  // kt in elements (multiple of 32)
    gld16(Ab + (size_t)rA0 * Kb2 + kt * 2 + oA0, (char*)As[buf] + LbA0);
    gld16(Ab + (size_t)rA1 * Kb2 + kt * 2 + oA1, (char*)As[buf] + LbA1);
    gld16(Bb + (size_t)rB  * Kb2 + kt * 2 + oB,  (char*)Bs[buf] + LbB);
  };

  const int nkt = K >> 5;              // 32
  stage(0, 0);
  stage(32, 1);
  SCHED_FENCE();
  for (int t = 0; t < nkt; ++t) {
    int cur = t - (t / 3) * 3;                 // t % 3
    if (t) {                                   // WAR: buf reused at t was read t-3
      SCHED_FENCE();
      __builtin_amdgcn_s_barrier();
      SCHED_FENCE();
    }
    if (t + 2 < nkt) {
      int nb = (t + 2) - ((t + 2) / 3) * 3;
      stage((t + 2) * 32, nb);
      SCHED_FENCE();
      asm volatile("s_waitcnt vmcnt(6)" ::: "memory");  // tile t complete
    } else if (t + 1 < nkt) {
      SCHED_FENCE();
      asm volatile("s_waitcnt vmcnt(3)" ::: "memory");
    } else {
      SCHED_FENCE();
      asm volatile("s_waitcnt vmcnt(0)" ::: "memory");
    }
    SCHED_FENCE();
    __builtin_amdgcn_s_barrier();      // RAW: buf[cur] ready for all waves
    SCHED_FENCE();
    const char* Ac = (const char*)As[cur];
    const char* Bc = (const char*)Bs[cur];
    bf16x8 af[4], bfr[4];
#pragma unroll
    for (int m = 0; m < 4; ++m) {
      int nat = (wr + m * 16 + l15) * 64 + l4 * 16;
      af[m] = *(const bf16x8*)(Ac + (nat ^ (((nat >> 7) & 3) << 4)));
    }
#pragma unroll
    for (int n = 0; n < 4; ++n) {
      int nat = (wc + n * 16 + l15) * 64 + l4 * 16;
      bfr[n] = *(const bf16x8*)(Bc + (nat ^ (((nat >> 7) & 3) << 4)));
    }
    __builtin_amdgcn_s_setprio(1);
#pragma unroll
    for (int m = 0; m < 4; ++m)
#pragma unroll
      for (int n = 0; n < 4; ++n)
        acc[m][n] = mfma16(af[m], bfr[n], acc[m][n]);
    __builtin_amdgcn_s_setprio(0);
  }
  // epilogue scatter: D col = lane&15, row = (lane>>4)*4 + reg
#pragma unroll
  for (int m = 0; m < 4; ++m) {
    int grow0 = bm * 256 + wr + m * 16 + l4 * 4;
#pragma unroll
    for (int n = 0; n < 4; ++n) {
      int gcol = bn * 128 + wc + n * 16 + l15;
      int which = gcol >> 10, rem = gcol & 1023;
      int h = rem >> 6, d = rem & 63;
      int b = grow0 >> 11, t0 = grow0 & 2047;
      if (which == 2) {
        // V^T [bh][d][t]: 4 consecutive-t bf16 -> one 8B store
        uint32_t lo = (uint32_t)f2b(acc[m][n][0]) | ((uint32_t)f2b(acc[m][n][1]) << 16);
        uint32_t hi = (uint32_t)f2b(acc[m][n][2]) | ((uint32_t)f2b(acc[m][n][3]) << 16);
        size_t off = (((size_t)(b * 16 + h)) * 64 + d) * 2048 + t0;
        *(uint2*)(vo + off) = make_uint2(lo, hi);
      } else {
        size_t off = (((size_t)(b * 16 + h)) * 2048 + t0) * 64 + d;
#pragma unroll
        for (int r = 0; r < 4; ++r) {
          float val = acc[m][n][r];
          if (which == 0) qo[off + (size_t)r * 64] = f2b(val * qscale);
          else            ko[off + (size_t)r * 64] = f2b(val);
        }
      }
    }
  }
}

// ------------------------------------------------ GEMM2: out-proj, fp32 out
// A [M][K] bf16, Bt [N][K] bf16. 128x128 tile, BK=32, 4 waves. Triple-buffer
// depth-2 counted vmcnt + both-sides swizzle.  [round-11/14 proven, ~20us]
__global__ __launch_bounds__(256) void k_gemm_out(const unsigned short* __restrict__ A,
                                                  const unsigned short* __restrict__ Bt,
                                                  int M, int N, int K,
                                                  float* __restrict__ Cf) {
  __shared__ unsigned short As[3][128 * 32];   // 24 KB
  __shared__ unsigned short Bs[3][128 * 32];   // 24 KB
  int tid = threadIdx.x;
  int w = tid >> 6, lane = tid & 63, l15 = lane & 15, l4 = lane >> 4;
  int nwg = gridDim.x;
  int gx = N >> 7;
  int lin = blockIdx.x;
  int nx = nwg >> 3, rr = nwg & 7;
  int xcd = lin & 7, idx = lin >> 3;
  int wgid = (xcd < rr ? xcd * (nx + 1) : rr * (nx + 1) + (xcd - rr) * nx) + idx;
  int bn = wgid % gx, bm = wgid / gx;
  int wr = (w >> 1) * 64, wc = (w & 1) * 64;
  f32x4 acc[4][4];
#pragma unroll
  for (int i = 0; i < 4; ++i)
#pragma unroll
    for (int j = 0; j < 4; ++j) acc[i][j] = (f32x4){0.f, 0.f, 0.f, 0.f};
  const char* Ab = (const char*)(A + (size_t)bm * 128 * K);
  const char* Bb = (const char*)(Bt + (size_t)bn * 128 * K);
  int Lb0 = tid * 16, Lb1 = (tid + 256) * 16;
  int Nb0 = Lb0 ^ (((Lb0 >> 7) & 3) << 4);
  int Nb1 = Lb1 ^ (((Lb1 >> 7) & 3) << 4);
  int rA0 = Nb0 >> 6, o0 = Nb0 & 63;
  int rA1 = Nb1 >> 6, o1 = Nb1 & 63;

  auto stage = [&](int kt, int buf) {
    gld16(Ab + ((size_t)rA0 * K + kt) * 2 + o0, (char*)As[buf] + Lb0);
    gld16(Bb + ((size_t)rA0 * K + kt) * 2 + o0, (char*)Bs[buf] + Lb0);
    gld16(Ab + ((size_t)rA1 * K + kt) * 2 + o1, (char*)As[buf] + Lb1);
    gld16(Bb + ((size_t)rA1 * K + kt) * 2 + o1, (char*)Bs[buf] + Lb1);
  };

  const int nkt = K >> 5;
  stage(0, 0);
  stage(32, 1);
  SCHED_FENCE();
  for (int t = 0; t < nkt; ++t) {
    int cur = t - (t / 3) * 3;
    if (t) {
      SCHED_FENCE();
      __builtin_amdgcn_s_barrier();
      SCHED_FENCE();
    }
    if (t + 2 < nkt) {
      int nb = (t + 2) - ((t + 2) / 3) * 3;
      stage((t + 2) * 32, nb);
      SCHED_FENCE();
      asm volatile("s_waitcnt vmcnt(8)" ::: "memory");
    } else if (t + 1 < nkt) {
      SCHED_FENCE();
      asm volatile("s_waitcnt vmcnt(4)" ::: "memory");
    } else {
      SCHED_FENCE();
      asm volatile("s_waitcnt vmcnt(0)" ::: "memory");
    }
    SCHED_FENCE();
    __builtin_amdgcn_s_barrier();
    SCHED_FENCE();
    const char* Ac = (const char*)As[cur];
    const char* Bc = (const char*)Bs[cur];
    bf16x8 af[4], bfr[4];
#pragma unroll
    for (int m = 0; m < 4; ++m) {
      int nat = (wr + m * 16 + l15) * 64 + l4 * 16;
      af[m] = *(const bf16x8*)(Ac + (nat ^ (((nat >> 7) & 3) << 4)));
    }
#pragma unroll
    for (int n = 0; n < 4; ++n) {
      int nat = (wc + n * 16 + l15) * 64 + l4 * 16;
      bfr[n] = *(const bf16x8*)(Bc + (nat ^ (((nat >> 7) & 3) << 4)));
    }
    __builtin_amdgcn_s_setprio(1);
#pragma unroll
    for (int m = 0; m < 4; ++m)
#pragma unroll
      for (int n = 0; n < 4; ++n)
        acc[m][n] = mfma16(af[m], bfr[n], acc[m][n]);
    __builtin_amdgcn_s_setprio(0);
  }
#pragma unroll
  for (int m = 0; m < 4; ++m) {
    int grow0 = bm * 128 + wr + m * 16 + l4 * 4;
#pragma unroll
    for (int n = 0; n < 4; ++n) {
      int gcol = bn * 128 + wc + n * 16 + l15;
#pragma unroll
      for (int r = 0; r < 4; ++r)
        Cf[(size_t)(grow0 + r) * N + gcol] = acc[m][n][r];
    }
  }
}

// ------------------------------------------------------------ flash attention
// Q,K: [bh][2048][64] bf16 (Q pre-scaled by 0.125*log2e); Vt: [bh][64][2048].
// 8 waves x 16 q-rows (QBLK=128); ONE q-tile per block, grid 1024,
// heavy-first. K/V double-buffered; double-barrier counted vmcnt(2).
// Fully-masked waves skip compute. LDS XOR swizzle: byte ^ ((row&7)<<4).
// [round-14 proven config — 72 us]
__global__ __launch_bounds__(512) void k_attn(const unsigned short* __restrict__ Q,
                                              const unsigned short* __restrict__ Kt,
                                              const unsigned short* __restrict__ Vt,
                                              unsigned short* __restrict__ AO) {
  __shared__ unsigned short Ks[2][4096];   // 16 KB  [64 kv][64 d]
  __shared__ unsigned short Vs[2][4096];   // 16 KB  [64 d][64 kv]
  __shared__ unsigned short Ps[8192];      // 16 KB  8 waves x [16 q][64 kv]
  int tid = threadIdx.x;
  int w = tid >> 6, lane = tid & 63, l15 = lane & 15, l4 = lane >> 4;
  int lin = blockIdx.x;
  int xcd = lin & 7, jj = lin >> 3;        // jj in 0..127
  int bh = xcd * 8 + (jj & 7);
  int qi = 15 - (jj >> 3);                 // 15 (heavy) .. 0 (light)
  const char* Kb = (const char*)(Kt + (size_t)bh * 2048 * 64);
  const char* Vb = (const char*)(Vt + (size_t)bh * 64 * 2048);
  const int swp = (l15 & 7) << 4;          // P-row swizzle for this lane
  char* Pw = (char*)Ps + w * 2048;
  int b = bh >> 4, h = bh & 15;

  int Lb0 = tid * 16;
  int Nb0 = Lb0 ^ (((Lb0 >> 7) & 7) << 4);
  int d0 = Nb0 >> 7, in0 = Nb0 & 127;

  auto stage = [&](int t, int buf) {
    size_t kv0 = (size_t)t * 64;
    gld16(Kb + kv0 * 128 + Nb0, (char*)Ks[buf] + Lb0);
    gld16(Vb + (size_t)d0 * 4096 + kv0 * 2 + in0, (char*)Vs[buf] + Lb0);
  };

  int q0 = qi * 128;
  const unsigned short* Qb = Q + ((size_t)bh * 2048 + q0 + w * 16) * 64;
  bf16x8 qf0 = *(const bf16x8*)((const char*)Qb + l15 * 128 + l4 * 16);
  bf16x8 qf1 = *(const bf16x8*)((const char*)Qb + l15 * 128 + 64 + l4 * 16);
  f32x4 o[4];
#pragma unroll
  for (int i = 0; i < 4; ++i) o[i] = (f32x4){0.f, 0.f, 0.f, 0.f};
  float mrow = -1e30f, lrow = 0.f;       // per-lane state for q = l15
  const int ntiles = 2 * qi + 2;
  const int qgmin = q0 + w * 16;         // this wave's lowest q row
  const int qg = qgmin + l15;            // per-lane q row
  stage(0, 0);
  SCHED_FENCE();
  for (int it = 0; it < ntiles; ++it) {
    int cur = it & 1;
    if (it) {                            // WAR: all waves done reading buf[cur^1]
      SCHED_FENCE();
      __builtin_amdgcn_s_barrier();
      SCHED_FENCE();
    }
    if (it + 1 < ntiles) {
      stage(it + 1, cur ^ 1);
      SCHED_FENCE();
      asm volatile("s_waitcnt vmcnt(2)" ::: "memory");  // tile it complete
    } else {
      SCHED_FENCE();
      asm volatile("s_waitcnt vmcnt(0)" ::: "memory");  // last tile: drain
    }
    SCHED_FENCE();
    __builtin_amdgcn_s_barrier();        // RAW: buf[cur] ready for all waves
    SCHED_FENCE();
    if (it * 64 <= qgmin + 15) {         // wave-uniform: not fully masked
      const char* Kc = (const char*)Ks[cur];
      const char* Vc = (const char*)Vs[cur];
      // S^T = K Q^T: lane holds s[c][r] = S[q=l15][kv=it*64+c*16+l4*4+r]
      f32x4 s[4];
      __builtin_amdgcn_s_setprio(1);
#pragma unroll
      for (int c = 0; c < 4; ++c) {
        int row = c * 16 + l15;
        int base = row * 128 + l4 * 16;
        int sw = (row & 7) << 4;
        bf16x8 k0 = *(const bf16x8*)(Kc + (base ^ sw));
        bf16x8 k1 = *(const bf16x8*)(Kc + ((base + 64) ^ sw));
        f32x4 t = mfma16(k0, qf0, (f32x4){0.f, 0.f, 0.f, 0.f});
        s[c] = mfma16(k1, qf1, t);
      }
      __builtin_amdgcn_s_setprio(0);
      if (it * 64 + 63 > qgmin) {        // diagonal-intersecting tile: mask
#pragma unroll
        for (int c = 0; c < 4; ++c) {
          int kvb = it * 64 + c * 16 + l4 * 4;
#pragma unroll
          for (int r = 0; r < 4; ++r)
            if (kvb + r > qg) s[c][r] = -1e30f;
        }
      }
      // online softmax: lane-local 16 + 2 shuffles
      float mx = fmaxf(fmaxf(fmaxf(s[0][0], s[0][1]), fmaxf(s[0][2], s[0][3])),
                       fmaxf(fmaxf(s[1][0], s[1][1]), fmaxf(s[1][2], s[1][3])));
      mx = fmaxf(mx, fmaxf(fmaxf(fmaxf(s[2][0], s[2][1]), fmaxf(s[2][2], s[2][3])),
                           fmaxf(fmaxf(s[3][0], s[3][1]), fmaxf(s[3][2], s[3][3]))));
      mx = fmaxf(mx, __shfl_xor(mx, 16));
      mx = fmaxf(mx, __shfl_xor(mx, 32));
      float mn = fmaxf(mrow, mx);
      float corr = __builtin_amdgcn_exp2f(mrow - mn);
      mrow = mn;
      float rs = 0.f;
#pragma unroll
      for (int c = 0; c < 4; ++c) {
        float p0 = __builtin_amdgcn_exp2f(s[c][0] - mn);
        float p1 = __builtin_amdgcn_exp2f(s[c][1] - mn);
        float p2 = __builtin_amdgcn_exp2f(s[c][2] - mn);
        float p3 = __builtin_amdgcn_exp2f(s[c][3] - mn);
        rs += (p0 + p1) + (p2 + p3);
        uint32_t lo = (uint32_t)f2b(p0) | ((uint32_t)f2b(p1) << 16);
        uint32_t hi = (uint32_t)f2b(p2) | ((uint32_t)f2b(p3) << 16);
        *(uint2*)(Pw + ((l15 * 128 + c * 32 + l4 * 8) ^ swp)) = make_uint2(lo, hi);
      }
      rs += __shfl_xor(rs, 16);
      rs += __shfl_xor(rs, 32);
      lrow = lrow * corr + rs;
      float corr_r[4];
#pragma unroll
      for (int r = 0; r < 4; ++r) corr_r[r] = __shfl(corr, l4 * 4 + r);
#pragma unroll
      for (int dc = 0; dc < 4; ++dc)
#pragma unroll
        for (int r = 0; r < 4; ++r) o[dc][r] *= corr_r[r];
      // O += P V
      bf16x8 pa[2];
#pragma unroll
      for (int kc = 0; kc < 2; ++kc)
        pa[kc] = *(const bf16x8*)(Pw + ((l15 * 128 + kc * 64 + l4 * 16) ^ swp));
      __builtin_amdgcn_s_setprio(1);
#pragma unroll
      for (int dc = 0; dc < 4; ++dc) {
#pragma unroll
        for (int kc = 0; kc < 2; ++kc) {
          int vrow = dc * 16 + l15;
          int vnat = vrow * 128 + kc * 64 + l4 * 16;
          bf16x8 vb = *(const bf16x8*)(Vc + (vnat ^ ((vrow & 7) << 4)));
          o[dc] = mfma16(pa[kc], vb, o[dc]);
        }
      }
      __builtin_amdgcn_s_setprio(0);
    }
  }
  float inv[4];
#pragma unroll
  for (int r = 0; r < 4; ++r) inv[r] = 1.f / __shfl(lrow, l4 * 4 + r);
#pragma unroll
  for (int dc = 0; dc < 4; ++dc) {
#pragma unroll
    for (int r = 0; r < 4; ++r) {
      int t = q0 + w * 16 + l4 * 4 + r;
      AO[((size_t)(b * 2048 + t)) * 1024 + h * 64 + dc * 16 + l15] =
          f2b(o[dc][r] * inv[r]);
    }
  }
}

// ---------------------------------------------------------------------------
extern "C" void kernel_launch(void* const* d_in, const int* in_sizes, int n_in,
                              void* d_out, int out_size, void* d_ws, size_t ws_size,
                              hipStream_t stream) {
  const float* x      = (const float*)d_in[0];   // [4,2048,1024]
  const float* w_qkv  = (const float*)d_in[1];   // [1024,3072]
  const float* w_proj = (const float*)d_in[2];   // [1024,1024]
  float* out = (float*)d_out;                    // [4,2048,1024] f32
  char* ws = (char*)d_ws;
  const size_t MB = 1024 * 1024;
  // xb and ao alias (ao written by attn after gemm1 consumed xb).
  unsigned short* xb     = (unsigned short*)(ws);            // 16MB [8192][1024]
  unsigned short* ao     = (unsigned short*)(ws);            // 16MB [8192][1024]
  unsigned short* wqkvT  = (unsigned short*)(ws + 16 * MB);  // 6MB [3072][1024]
  unsigned short* wprojT = (unsigned short*)(ws + 22 * MB);  // 2MB [1024][1024]
  unsigned short* q      = (unsigned short*)(ws + 24 * MB);  // 16MB [64][2048][64]
  unsigned short* k      = (unsigned short*)(ws + 40 * MB);  // 16MB
  unsigned short* vT     = (unsigned short*)(ws + 56 * MB);  // 16MB [64][64][2048]

  const float qscale = 0.125f * 1.44269504088896f;  // hd^-0.5 * log2(e)
  k_prep<<<5120, 256, 0, stream>>>(x, xb, w_qkv, wqkvT, w_proj, wprojT);
  k_gemmQKV<<<768, 512, 0, stream>>>(xb, wqkvT, q, k, vT, qscale);
  k_attn<<<1024, 512, 0, stream>>>(q, k, vT, ao);
  k_gemm_out<<<512, 256, 0, stream>>>(ao, wprojT, 8192, 1024, 1024, out);
}